// Round 13
// baseline (60.682 us; speedup 1.0000x reference)
//
#include <hip/hip_runtime.h>

// GAT: N=4096, F_IN=128, F_HID=64, H=4, F_OUT=64, alpha=0.2
#define GN 4096
#define F_IN 128
#define F_HID 64
#define NHEADS 4
#define F_OUT 64
#define ALPHA 0.2f
#define NGEMM 512          // GEMM blocks in K1 (8 nodes each), placed FIRST

// workspace layout (bytes)
#define OFF_WH     0           // GN*256*4 = 4 MB   [i][head*64+f]
#define OFF_SRC1   4194304     // GN*4*4             [i][head]
#define OFF_DST1   4259840     // GN*4*4
#define OFF_HCAT   4325376     // GN*256*4 = 4 MB
#define OFF_WH2    8519680     // GN*64*4 = 1 MB
#define OFF_SRC2   9568256     // GN*4
#define OFF_DST2   9584640     // GN*4
#define OFF_BM     9601024     // GN*256 ushort = 2 MB

// ===== K1: [GEMM blocks 0..511] + [bitmask scan blocks 512..4607, 1 row each] =====
__global__ __launch_bounds__(256) void prep_kernel(
        const float* __restrict__ adj, const float* __restrict__ x,
        const float* __restrict__ linW, const float* __restrict__ linb,
        const float* __restrict__ Wheads, const float* __restrict__ aheads,
        float* __restrict__ Wh, float* __restrict__ src1, float* __restrict__ dst1,
        unsigned short* __restrict__ bm) {
    __shared__ struct { float xs[8][128]; float hs[8][128]; } sm;
    const int tid = threadIdx.x;

    if (blockIdx.x >= NGEMM) {
        const int row = blockIdx.x - NGEMM;
        const float4* a4 = (const float4*)(adj + (size_t)row * GN) + tid * 4;
        float4 v0 = a4[0], v1 = a4[1], v2 = a4[2], v3 = a4[3];
        unsigned msk = 0;
        msk |= (v0.x > 0.0f) ? 1u : 0u;         msk |= (v0.y > 0.0f) ? 2u : 0u;
        msk |= (v0.z > 0.0f) ? 4u : 0u;         msk |= (v0.w > 0.0f) ? 8u : 0u;
        msk |= (v1.x > 0.0f) ? 16u : 0u;        msk |= (v1.y > 0.0f) ? 32u : 0u;
        msk |= (v1.z > 0.0f) ? 64u : 0u;        msk |= (v1.w > 0.0f) ? 128u : 0u;
        msk |= (v2.x > 0.0f) ? 256u : 0u;       msk |= (v2.y > 0.0f) ? 512u : 0u;
        msk |= (v2.z > 0.0f) ? 1024u : 0u;      msk |= (v2.w > 0.0f) ? 2048u : 0u;
        msk |= (v3.x > 0.0f) ? 4096u : 0u;      msk |= (v3.y > 0.0f) ? 8192u : 0u;
        msk |= (v3.z > 0.0f) ? 16384u : 0u;     msk |= (v3.w > 0.0f) ? 32768u : 0u;
        bm[row * 256 + tid] = (unsigned short)msk;
        return;
    }

    // ---- fused GEMMs: h = x@linW+b ; Wh = h@W_heads ; src1/dst1 (8 nodes) ----
    const int i0 = blockIdx.x * 8;
    #pragma unroll
    for (int t = 0; t < 4; ++t) {
        int e = t * 256 + tid;
        sm.xs[e >> 7][e & 127] = x[(size_t)i0 * 128 + e];
    }
    __syncthreads();
    {
        const int k = tid & 127;
        const int n0 = tid >> 7;
        float bk = linb[k];
        float a0 = bk, a1 = bk, a2 = bk, a3 = bk;
        for (int j = 0; j < 128; ++j) {
            float w = linW[j * 128 + k];
            a0 += sm.xs[n0][j] * w;
            a1 += sm.xs[n0 + 2][j] * w;
            a2 += sm.xs[n0 + 4][j] * w;
            a3 += sm.xs[n0 + 6][j] * w;
        }
        sm.hs[n0][k] = a0; sm.hs[n0 + 2][k] = a1;
        sm.hs[n0 + 4][k] = a2; sm.hs[n0 + 6][k] = a3;
    }
    __syncthreads();
    {
        const int hd = tid >> 6, f = tid & 63;
        float acc[8] = {0, 0, 0, 0, 0, 0, 0, 0};
        const float* Wp = Wheads + (size_t)hd * F_IN * F_HID + f;
        for (int j = 0; j < 128; ++j) {
            float w = Wp[j * 64];
            #pragma unroll
            for (int n = 0; n < 8; ++n) acc[n] += sm.hs[n][j] * w;
        }
        const float as = aheads[hd * 128 + f];
        const float ad = aheads[hd * 128 + 64 + f];
        #pragma unroll
        for (int n = 0; n < 8; ++n) {
            Wh[(size_t)(i0 + n) * 256 + hd * 64 + f] = acc[n];
            float sv = acc[n] * as, dv = acc[n] * ad;
            #pragma unroll
            for (int o = 32; o > 0; o >>= 1) {
                sv += __shfl_xor(sv, o, 64);
                dv += __shfl_xor(dv, o, 64);
            }
            if (f == 0) { src1[(i0 + n) * 4 + hd] = sv; dst1[(i0 + n) * 4 + hd] = dv; }
        }
    }
}

// --- per-wave: build row's neighbor list from bitmask into LDS; returns deg ---
__device__ __forceinline__ int build_row_nbrs(const unsigned short* __restrict__ bm,
                                              int row, int lane, int* sidx) {
    unsigned long long bits =
        ((const unsigned long long*)(bm + (size_t)row * 256))[lane];
    int c = __popcll(bits);
    int inc = c;
    #pragma unroll
    for (int o = 1; o < 64; o <<= 1) {
        int n = __shfl_up(inc, o, 64);
        if (lane >= o) inc += n;
    }
    int p = inc - c;
    const int deg = __shfl(inc, 63, 64);
    const int col0 = lane * 64;
    while (bits) {
        int k = __ffsll((long long)bits) - 1;
        if (p < 136) sidx[p] = col0 + k;
        ++p;
        bits &= bits - 1;
    }
    const int deg4 = (deg + 3) & ~3;
    if (lane < deg4 - deg) sidx[deg + lane] = 0;   // pads: weight will be exactly 0
    return deg;
}

// ===== K2: layer-1 attention; ONE BLOCK PER ROW, wave = head (16384 waves) =====
__global__ __launch_bounds__(256) void attn1_kernel(
        const float* __restrict__ Wh, const float* __restrict__ src1,
        const float* __restrict__ dst1, const unsigned short* __restrict__ bm,
        float* __restrict__ hcat) {
    __shared__ int   sidx[136];
    __shared__ int   sdeg;
    __shared__ float ps[4][136];       // [head][nbr] normalized weights
    const int hd   = threadIdx.x >> 6;
    const int lane = threadIdx.x & 63;
    const int row  = blockIdx.x;

    if (hd == 0) {
        int d = build_row_nbrs(bm, row, lane, sidx);
        if (lane == 0) sdeg = d;
    }
    __syncthreads();
    const int deg = sdeg;
    const int nchunk = (deg + 63) >> 6;

    // phase 1: this wave's head; lanes over neighbors
    const float s_i = src1[row * 4 + hd];
    float e[3];
    float m = -1e30f;
    for (int c = 0; c < nchunk; ++c) {
        int t = c * 64 + lane;
        float ev = -1e30f;
        if (t < deg) {
            int j = sidx[t];
            ev = s_i + dst1[j * 4 + hd];
            ev = (ev > 0.0f) ? ev : ALPHA * ev;
        }
        e[c] = ev; m = fmaxf(m, ev);
    }
    #pragma unroll
    for (int o = 32; o > 0; o >>= 1) m = fmaxf(m, __shfl_xor(m, o, 64));
    float l = 0.0f;
    for (int c = 0; c < nchunk; ++c) { e[c] = expf(e[c] - m); l += e[c]; }
    #pragma unroll
    for (int o = 32; o > 0; o >>= 1) l += __shfl_xor(l, o, 64);
    const float inv = 1.0f / l;
    for (int c = 0; c < nchunk; ++c) ps[hd][c * 64 + lane] = e[c] * inv;
    // own wave wrote ps[hd]; no cross-wave use -> no barrier

    // phase 2: lane = (q = nbr sub 0-3, f4 = 16 float4 cols of this head)
    const int q  = lane >> 4;
    const int f4 = lane & 15;
    const float4* Wh4 = (const float4*)Wh;
    float4 acc = make_float4(0.f, 0.f, 0.f, 0.f);
    const int deg4 = (deg + 3) & ~3;
    for (int t = 0; t < deg4; t += 4) {
        int   j = sidx[t + q];
        float p = ps[hd][t + q];
        float4 w = Wh4[(size_t)j * 64 + hd * 16 + f4];
        acc.x += p * w.x; acc.y += p * w.y; acc.z += p * w.z; acc.w += p * w.w;
    }
    // fold the 4 q-groups (lanes differing in bits 4,5)
    #pragma unroll
    for (int o = 16; o <= 32; o <<= 1) {
        acc.x += __shfl_xor(acc.x, o, 64);
        acc.y += __shfl_xor(acc.y, o, 64);
        acc.z += __shfl_xor(acc.z, o, 64);
        acc.w += __shfl_xor(acc.w, o, 64);
    }
    if (q == 0) {
        acc.x = (acc.x > 0.0f) ? acc.x : expm1f(acc.x);
        acc.y = (acc.y > 0.0f) ? acc.y : expm1f(acc.y);
        acc.z = (acc.z > 0.0f) ? acc.z : expm1f(acc.z);
        acc.w = (acc.w > 0.0f) ? acc.w : expm1f(acc.w);
        ((float4*)hcat)[(size_t)row * 64 + hd * 16 + f4] = acc;
    }
}

// ===== K3: tiled GEMM Wh2 = hcat @ Wend (+ src2/dst2); 8 nodes/block =====
__global__ __launch_bounds__(256) void wh2_kernel(
        const float* __restrict__ hcat, const float* __restrict__ Wend,
        const float* __restrict__ aend, float* __restrict__ Wh2,
        float* __restrict__ src2, float* __restrict__ dst2) {
    __shared__ float cs[8][256];       // hcat tile (8 KB)
    __shared__ float wt[32][64];       // Wend tile (8 KB)
    const int tid  = threadIdx.x;
    const int lane = tid & 63;
    const int n0   = tid >> 6;         // nodes {n0, n0+4}
    const int i0   = blockIdx.x * 8;
    #pragma unroll
    for (int t = 0; t < 8; ++t) {
        int e = t * 256 + tid;
        cs[e >> 8][e & 255] = hcat[(size_t)i0 * 256 + e];
    }
    __syncthreads();
    float a0 = 0.f, a1 = 0.f;
    for (int tile = 0; tile < 8; ++tile) {
        const float4* Wsrc = (const float4*)(Wend + tile * 32 * 64);
        ((float4*)wt)[tid]       = Wsrc[tid];
        ((float4*)wt)[tid + 256] = Wsrc[tid + 256];
        __syncthreads();
        const int jb = tile * 32;
        #pragma unroll
        for (int jj = 0; jj < 32; ++jj) {
            float w = wt[jj][lane];
            a0 += cs[n0][jb + jj] * w;
            a1 += cs[n0 + 4][jb + jj] * w;
        }
        __syncthreads();
    }
    Wh2[(size_t)(i0 + n0) * 64 + lane] = a0;
    Wh2[(size_t)(i0 + n0 + 4) * 64 + lane] = a1;
    const float as = aend[lane], ad = aend[64 + lane];
    float s0 = a0 * as, d0 = a0 * ad, s1 = a1 * as, d1 = a1 * ad;
    #pragma unroll
    for (int o = 32; o > 0; o >>= 1) {
        s0 += __shfl_xor(s0, o, 64); d0 += __shfl_xor(d0, o, 64);
        s1 += __shfl_xor(s1, o, 64); d1 += __shfl_xor(d1, o, 64);
    }
    if (lane == 0) {
        src2[i0 + n0] = s0;     dst2[i0 + n0] = d0;
        src2[i0 + n0 + 4] = s1; dst2[i0 + n0 + 4] = d1;
    }
}

// ===== K4: layer-2 attention + elu + final row softmax; wave per row =====
__global__ __launch_bounds__(256) void attn2_kernel(
        const float* __restrict__ Wh2, const float* __restrict__ src,
        const float* __restrict__ dst, const unsigned short* __restrict__ bm,
        float* __restrict__ out) {
    __shared__ int sidx[4][136];
    const int wave = threadIdx.x >> 6;
    const int lane = threadIdx.x & 63;
    const int row  = blockIdx.x * 4 + wave;

    const int deg = build_row_nbrs(bm, row, lane, sidx[wave]);
    const int* nb = sidx[wave];
    const float s_i = src[row];

    float e[2];
    #pragma unroll
    for (int c = 0; c < 2; ++c) {
        int t = c * 64 + lane;
        float ev = -1e30f;
        if (t < deg) {
            int j = nb[t];
            ev = s_i + dst[j];
            ev = (ev > 0.0f) ? ev : ALPHA * ev;
        }
        e[c] = ev;
    }
    float m = fmaxf(e[0], e[1]);
    #pragma unroll
    for (int o = 32; o > 0; o >>= 1) m = fmaxf(m, __shfl_xor(m, o, 64));
    float l = 0.0f;
    #pragma unroll
    for (int c = 0; c < 2; ++c) { e[c] = expf(e[c] - m); l += e[c]; }
    #pragma unroll
    for (int o = 32; o > 0; o >>= 1) l += __shfl_xor(l, o, 64);

    float accA = 0.0f, accB = 0.0f;
    const float* W2 = Wh2 + lane;
    #pragma unroll
    for (int c = 0; c < 2; ++c) {
        int base = c * 64;
        if (base >= deg) break;
        int nmax = deg - base; if (nmax > 64) nmax = 64;
        int n4 = (nmax + 3) & ~3;
        for (int t = 0; t < n4; t += 4) {
            int4 jj = *(const int4*)(nb + base + t);
            float w0 = W2[(size_t)jj.x * 64];
            float w1 = W2[(size_t)jj.y * 64];
            float w2 = W2[(size_t)jj.z * 64];
            float w3 = W2[(size_t)jj.w * 64];
            float p0 = __shfl(e[c], t, 64),     p1 = __shfl(e[c], t + 1, 64);
            float p2 = __shfl(e[c], t + 2, 64), p3 = __shfl(e[c], t + 3, 64);
            accA += p0 * w0 + p2 * w2;
            accB += p1 * w1 + p3 * w3;
        }
    }
    float v = (accA + accB) / l;
    v = (v > 0.0f) ? v : expm1f(v);    // elu

    float mm = v;
    #pragma unroll
    for (int o = 32; o > 0; o >>= 1) mm = fmaxf(mm, __shfl_xor(mm, o, 64));
    float ee = expf(v - mm);
    float ss = ee;
    #pragma unroll
    for (int o = 32; o > 0; o >>= 1) ss += __shfl_xor(ss, o, 64);
    out[(size_t)row * F_OUT + lane] = ee / ss;
}

extern "C" void kernel_launch(void* const* d_in, const int* in_sizes, int n_in,
                              void* d_out, int out_size, void* d_ws, size_t ws_size,
                              hipStream_t stream) {
    const float* x      = (const float*)d_in[0];
    const float* adj    = (const float*)d_in[1];
    const float* lin_W  = (const float*)d_in[2];
    const float* lin_b  = (const float*)d_in[3];
    const float* Wheads = (const float*)d_in[4];
    const float* aheads = (const float*)d_in[5];
    const float* Wend   = (const float*)d_in[6];
    const float* aend   = (const float*)d_in[7];
    float* out = (float*)d_out;

    char* ws = (char*)d_ws;
    float* Wh   = (float*)(ws + OFF_WH);
    float* src1 = (float*)(ws + OFF_SRC1);
    float* dst1 = (float*)(ws + OFF_DST1);
    float* hcat = (float*)(ws + OFF_HCAT);
    float* Wh2  = (float*)(ws + OFF_WH2);
    float* src2 = (float*)(ws + OFF_SRC2);
    float* dst2 = (float*)(ws + OFF_DST2);
    unsigned short* bm = (unsigned short*)(ws + OFF_BM);

    prep_kernel<<<NGEMM + GN, 256, 0, stream>>>(adj, x, lin_W, lin_b, Wheads, aheads,
                                                Wh, src1, dst1, bm);
    attn1_kernel<<<GN, 256, 0, stream>>>(Wh, src1, dst1, bm, hcat);
    wh2_kernel<<<GN / 8, 256, 0, stream>>>(hcat, Wend, aend, Wh2, src2, dst2);
    attn2_kernel<<<GN / 4, 256, 0, stream>>>(Wh2, src2, dst2, bm, out);
}